// Round 1
// baseline (4051.631 us; speedup 1.0000x reference)
//
#include <hip/hip_runtime.h>
#include <math.h>

// Problem constants (fixed by setup_inputs)
#define LQ 1024
#define BZ 8
#define D  512
#define NH 8
#define DH 64
#define IOU_THR 0.2f
#define COS_THR 0.2f

// ---------------------------------------------------------------------------
// Kernel 1: h[b][i][:] = query[i][b][:]; rnorm[b*LQ+i] = 1/max(||row||,1e-8)
// ---------------------------------------------------------------------------
__global__ __launch_bounds__(256) void prep_kernel(const float* __restrict__ query,
                                                   float* __restrict__ h,
                                                   float* __restrict__ rnorm) {
    int blk = blockIdx.x;            // b*LQ + i
    int b = blk >> 10, i = blk & 1023;
    const float* src = query + ((size_t)i * BZ + b) * D;
    float*       dst = h + (size_t)blk * D;
    int tid = threadIdx.x;
    float2 v = ((const float2*)src)[tid];   // 256 threads x 2 = 512 elems
    ((float2*)dst)[tid] = v;
    float ss = v.x * v.x + v.y * v.y;
    __shared__ float red[256];
    red[tid] = ss; __syncthreads();
    for (int s = 128; s > 0; s >>= 1) {
        if (tid < s) red[tid] += red[tid + s];
        __syncthreads();
    }
    if (tid == 0) rnorm[blk] = 1.0f / fmaxf(sqrtf(red[0]), 1e-8f);
}

// ---------------------------------------------------------------------------
// Kernel 2: mask[b][i][j] = !(((iou<=0.2)||(i==j)) && (cos>0.2))
// cos via 32x32-tiled fp32 GEMM of rnorm-scaled h rows.
// ---------------------------------------------------------------------------
__global__ __launch_bounds__(256) void mask_kernel(const float* __restrict__ h,
                                                   const float* __restrict__ rnorm,
                                                   const float* __restrict__ segments,
                                                   unsigned char* __restrict__ mask) {
    int b  = blockIdx.z;
    int i0 = blockIdx.y * 32;
    int j0 = blockIdx.x * 32;
    __shared__ float As[32][33], Bs[32][33];
    int tid = threadIdx.x;
    int ty = tid >> 4, tx = tid & 15;
    float acc00 = 0.f, acc01 = 0.f, acc10 = 0.f, acc11 = 0.f;
    const float* hb = h + (size_t)b * LQ * D;
    const float* rn = rnorm + b * LQ;
    int r  = tid >> 3;           // 0..31
    int c4 = (tid & 7) * 4;      // 0..28
    float ra = rn[i0 + r];
    float rb = rn[j0 + r];
    for (int k0 = 0; k0 < D; k0 += 32) {
        float4 a4 = *(const float4*)&hb[(size_t)(i0 + r) * D + k0 + c4];
        As[r][c4 + 0] = a4.x * ra; As[r][c4 + 1] = a4.y * ra;
        As[r][c4 + 2] = a4.z * ra; As[r][c4 + 3] = a4.w * ra;
        float4 b4 = *(const float4*)&hb[(size_t)(j0 + r) * D + k0 + c4];
        Bs[r][c4 + 0] = b4.x * rb; Bs[r][c4 + 1] = b4.y * rb;
        Bs[r][c4 + 2] = b4.z * rb; Bs[r][c4 + 3] = b4.w * rb;
        __syncthreads();
        #pragma unroll
        for (int k = 0; k < 32; k++) {
            float a0 = As[ty * 2][k], a1 = As[ty * 2 + 1][k];
            float b0 = Bs[tx * 2][k], b1 = Bs[tx * 2 + 1][k];
            acc00 += a0 * b0; acc01 += a0 * b1;
            acc10 += a1 * b0; acc11 += a1 * b1;
        }
        __syncthreads();
    }
    const float* seg = segments + (size_t)b * LQ * 2;
    float accs[2][2] = {{acc00, acc01}, {acc10, acc11}};
    #pragma unroll
    for (int ii = 0; ii < 2; ii++) {
        int i = i0 + ty * 2 + ii;
        float ci = seg[i * 2], li = seg[i * 2 + 1];
        float si = ci - li * 0.5f, ei = ci + li * 0.5f;
        #pragma unroll
        for (int jj = 0; jj < 2; jj++) {
            int j = j0 + tx * 2 + jj;
            float cj = seg[j * 2], lj = seg[j * 2 + 1];
            float sj = cj - lj * 0.5f, ej = cj + lj * 0.5f;
            float inter = fmaxf(fminf(ei, ej) - fmaxf(si, sj), 0.0f);
            float uni   = li + lj - inter;
            float iou   = inter / uni;
            float cosv  = accs[ii][jj];
            bool adj = ((iou <= IOU_THR) || (i == j)) && (cosv > COS_THR);
            mask[((size_t)b * LQ + i) * LQ + j] = adj ? 0 : 1;  // 1 = masked
        }
    }
}

// ---------------------------------------------------------------------------
// Kernel 3: Q/K/V = h @ W^T + bias, 32x32-tiled fp32 GEMM, z selects matrix
// h: [8192][512]; W: [512][512] row-major (row n is k-contiguous)
// ---------------------------------------------------------------------------
__global__ __launch_bounds__(256) void qkv_kernel(const float* __restrict__ h,
                                                  const float* __restrict__ Wq, const float* __restrict__ bq,
                                                  const float* __restrict__ Wk, const float* __restrict__ bk,
                                                  const float* __restrict__ Wv, const float* __restrict__ bv,
                                                  float* __restrict__ Q, float* __restrict__ K,
                                                  float* __restrict__ V) {
    const float* W; const float* bias; float* C;
    if (blockIdx.z == 0)      { W = Wq; bias = bq; C = Q; }
    else if (blockIdx.z == 1) { W = Wk; bias = bk; C = K; }
    else                      { W = Wv; bias = bv; C = V; }
    int m0 = blockIdx.x * 32, n0 = blockIdx.y * 32;
    __shared__ float As[32][33], Bs[32][33];
    int tid = threadIdx.x;
    int ty = tid >> 4, tx = tid & 15;
    float acc00 = 0.f, acc01 = 0.f, acc10 = 0.f, acc11 = 0.f;
    int r  = tid >> 3;
    int c4 = (tid & 7) * 4;
    for (int k0 = 0; k0 < D; k0 += 32) {
        float4 a4 = *(const float4*)&h[(size_t)(m0 + r) * D + k0 + c4];
        As[r][c4 + 0] = a4.x; As[r][c4 + 1] = a4.y;
        As[r][c4 + 2] = a4.z; As[r][c4 + 3] = a4.w;
        float4 b4 = *(const float4*)&W[(size_t)(n0 + r) * D + k0 + c4];
        Bs[r][c4 + 0] = b4.x; Bs[r][c4 + 1] = b4.y;
        Bs[r][c4 + 2] = b4.z; Bs[r][c4 + 3] = b4.w;
        __syncthreads();
        #pragma unroll
        for (int k = 0; k < 32; k++) {
            float a0 = As[ty * 2][k], a1 = As[ty * 2 + 1][k];
            float b0 = Bs[tx * 2][k], b1 = Bs[tx * 2 + 1][k];
            acc00 += a0 * b0; acc01 += a0 * b1;
            acc10 += a1 * b0; acc11 += a1 * b1;
        }
        __syncthreads();
    }
    int mi = m0 + ty * 2, nj = n0 + tx * 2;
    float bj0 = bias[nj], bj1 = bias[nj + 1];
    C[(size_t)mi * D + nj]           = acc00 + bj0;
    C[(size_t)mi * D + nj + 1]       = acc01 + bj1;
    C[(size_t)(mi + 1) * D + nj]     = acc10 + bj0;
    C[(size_t)(mi + 1) * D + nj + 1] = acc11 + bj1;
}

// ---------------------------------------------------------------------------
// Kernel 4: per (b,h,i) row attention: scores -> softmax -> PV, +h, transpose
// ---------------------------------------------------------------------------
__global__ __launch_bounds__(128) void attn_kernel(const float* __restrict__ Q,
                                                   const float* __restrict__ K,
                                                   const float* __restrict__ V,
                                                   const unsigned char* __restrict__ mask,
                                                   const float* __restrict__ h,
                                                   float* __restrict__ out) {
    int i  = blockIdx.x;
    int hh = blockIdx.y;
    int b  = blockIdx.z;
    int tid = threadIdx.x;
    __shared__ float4 q_s[16];
    __shared__ float  p_s[LQ];
    __shared__ float  red[128];
    const float* qrow = Q + (((size_t)b * LQ + i) * NH + hh) * DH;
    if (tid < 16) q_s[tid] = ((const float4*)qrow)[tid];
    __syncthreads();
    const unsigned char* mrow = mask + ((size_t)b * LQ + i) * LQ;
    float lmax = -INFINITY;
    for (int j = tid; j < LQ; j += 128) {
        float sc;
        if (mrow[j]) {
            sc = -INFINITY;
        } else {
            const float4* krow = (const float4*)(K + (((size_t)b * LQ + j) * NH + hh) * DH);
            float dot = 0.f;
            #pragma unroll
            for (int m = 0; m < 16; m++) {
                float4 kq = krow[m]; float4 qq = q_s[m];
                dot += qq.x * kq.x + qq.y * kq.y + qq.z * kq.z + qq.w * kq.w;
            }
            sc = dot * 0.125f;  // 1/sqrt(64)
        }
        p_s[j] = sc;
        lmax = fmaxf(lmax, sc);
    }
    red[tid] = lmax; __syncthreads();
    for (int s = 64; s > 0; s >>= 1) {
        if (tid < s) red[tid] = fmaxf(red[tid], red[tid + s]);
        __syncthreads();
    }
    float mx = red[0]; __syncthreads();
    float lsum = 0.f;
    for (int j = tid; j < LQ; j += 128) {
        float e = __expf(p_s[j] - mx);   // exp(-inf)=0 handles masked
        p_s[j] = e;
        lsum += e;
    }
    red[tid] = lsum; __syncthreads();
    for (int s = 64; s > 0; s >>= 1) {
        if (tid < s) red[tid] += red[tid + s];
        __syncthreads();
    }
    float denom = red[0]; __syncthreads();
    // PV: thread t owns output element t; coalesced V reads across t
    int half = tid >> 6, t = tid & 63;
    const float* Vb = V + ((size_t)b * LQ * NH) * DH + hh * DH + t;
    float acc = 0.f;
    int j0 = half * 512;
    for (int j = j0; j < j0 + 512; j++) {
        acc += p_s[j] * Vb[(size_t)j * (NH * DH)];
    }
    red[tid] = acc; __syncthreads();
    if (tid < 64) {
        float val = (red[tid] + red[tid + 64]) / denom;
        val += h[((size_t)b * LQ + i) * D + hh * DH + tid];
        out[((size_t)i * BZ + b) * D + hh * DH + tid] = val;
    }
}

// ---------------------------------------------------------------------------
extern "C" void kernel_launch(void* const* d_in, const int* in_sizes, int n_in,
                              void* d_out, int out_size, void* d_ws, size_t ws_size,
                              hipStream_t stream) {
    const float* query    = (const float*)d_in[0];
    const float* segments = (const float*)d_in[1];
    const float* Wq = (const float*)d_in[2];
    const float* bq = (const float*)d_in[3];
    const float* Wk = (const float*)d_in[4];
    const float* bk = (const float*)d_in[5];
    const float* Wv = (const float*)d_in[6];
    const float* bv = (const float*)d_in[7];
    float* out = (float*)d_out;

    // Workspace layout (~75.5 MB)
    float* h     = (float*)d_ws;                       // 8*1024*512
    float* Q     = h + (size_t)BZ * LQ * D;
    float* K     = Q + (size_t)BZ * LQ * D;
    float* V     = K + (size_t)BZ * LQ * D;
    float* rnorm = V + (size_t)BZ * LQ * D;            // 8192
    unsigned char* mask = (unsigned char*)(rnorm + BZ * LQ);  // 8*1024*1024 bytes

    prep_kernel<<<BZ * LQ, 256, 0, stream>>>(query, h, rnorm);
    mask_kernel<<<dim3(LQ / 32, LQ / 32, BZ), 256, 0, stream>>>(h, rnorm, segments, mask);
    qkv_kernel<<<dim3(BZ * LQ / 32, D / 32, 3), 256, 0, stream>>>(h, Wq, bq, Wk, bk, Wv, bv, Q, K, V);
    attn_kernel<<<dim3(LQ, NH, BZ), 128, 0, stream>>>(Q, K, V, mask, h, out);
}

// Round 2
// 478.100 us; speedup vs baseline: 8.4745x; 8.4745x over previous
//
#include <hip/hip_runtime.h>
#include <math.h>

#define LQ 1024
#define BZ 8
#define D  512
#define NH 8
#define DH 64
#define IOU_THR 0.2f
#define COS_THR 0.2f
#define NEG (-1e30f)

typedef short bf16x8 __attribute__((ext_vector_type(8)));
typedef float f32x4  __attribute__((ext_vector_type(4)));

__device__ inline unsigned short f2bf(float x) {
    union { float f; unsigned int u; } v; v.f = x;
    unsigned int r = v.u + 0x7FFF + ((v.u >> 16) & 1);
    return (unsigned short)(r >> 16);
}

// ---------------------------------------------------------------------------
// Kernel 1: h[b][i][:] = query[i][b][:] (fp32 + bf16); rnorm = 1/max(||row||,1e-8)
// ---------------------------------------------------------------------------
__global__ __launch_bounds__(256) void prep_kernel(const float* __restrict__ query,
                                                   float* __restrict__ h,
                                                   unsigned short* __restrict__ hb,
                                                   float* __restrict__ rnorm) {
    int blk = blockIdx.x;            // b*LQ + i
    int b = blk >> 10, i = blk & 1023;
    const float* src = query + ((size_t)i * BZ + b) * D;
    float*          dst  = h  + (size_t)blk * D;
    unsigned short* dstb = hb + (size_t)blk * D;
    int tid = threadIdx.x;
    float2 v = ((const float2*)src)[tid];   // 256 threads x 2 = 512 elems
    ((float2*)dst)[tid] = v;
    unsigned int packed = (unsigned int)f2bf(v.x) | ((unsigned int)f2bf(v.y) << 16);
    ((unsigned int*)dstb)[tid] = packed;
    float ss = v.x * v.x + v.y * v.y;
    __shared__ float red[256];
    red[tid] = ss; __syncthreads();
    for (int s = 128; s > 0; s >>= 1) {
        if (tid < s) red[tid] += red[tid + s];
        __syncthreads();
    }
    if (tid == 0) rnorm[blk] = 1.0f / fmaxf(sqrtf(red[0]), 1e-8f);
}

// ---------------------------------------------------------------------------
// Kernel 2: convert Wq/Wk/Wv fp32 -> bf16 (concatenated)
// ---------------------------------------------------------------------------
__global__ __launch_bounds__(256) void cvt_w_kernel(const float* __restrict__ Wq,
                                                    const float* __restrict__ Wk,
                                                    const float* __restrict__ Wv,
                                                    unsigned short* __restrict__ Wb) {
    int t = blockIdx.x * 256 + threadIdx.x;      // 3*65536 threads, 4 elems each
    int mat = t >> 16;
    int off = (t & 65535) * 4;
    const float* src = (mat == 0) ? Wq : (mat == 1) ? Wk : Wv;
    float4 v = *(const float4*)(src + off);
    uint2 p;
    p.x = (unsigned int)f2bf(v.x) | ((unsigned int)f2bf(v.y) << 16);
    p.y = (unsigned int)f2bf(v.z) | ((unsigned int)f2bf(v.w) << 16);
    *(uint2*)(Wb + (size_t)mat * D * D + off) = p;
}

// ---------------------------------------------------------------------------
// Kernel 3: mask, fp32 cos GEMM 64x64 tile, 4x4 per thread
// ---------------------------------------------------------------------------
__global__ __launch_bounds__(256) void mask_kernel(const float* __restrict__ h,
                                                   const float* __restrict__ rnorm,
                                                   const float* __restrict__ segments,
                                                   unsigned char* __restrict__ mask) {
    int b  = blockIdx.z;
    int i0 = blockIdx.y * 64;
    int j0 = blockIdx.x * 64;
    __shared__ float As[16][68], Bs[16][68];
    int tid = threadIdx.x;
    int ty = tid >> 4, tx = tid & 15;
    const float* hb = h + (size_t)b * LQ * D;
    const float* rn = rnorm + b * LQ;
    float acc[4][4] = {};
    int lr = tid & 63;
    int lk = (tid >> 6) * 4;
    float ra  = rn[i0 + lr];
    float rb2 = rn[j0 + lr];
    for (int k0 = 0; k0 < D; k0 += 16) {
        float4 a4 = *(const float4*)&hb[(size_t)(i0 + lr) * D + k0 + lk];
        As[lk + 0][lr] = a4.x * ra; As[lk + 1][lr] = a4.y * ra;
        As[lk + 2][lr] = a4.z * ra; As[lk + 3][lr] = a4.w * ra;
        float4 b4 = *(const float4*)&hb[(size_t)(j0 + lr) * D + k0 + lk];
        Bs[lk + 0][lr] = b4.x * rb2; Bs[lk + 1][lr] = b4.y * rb2;
        Bs[lk + 2][lr] = b4.z * rb2; Bs[lk + 3][lr] = b4.w * rb2;
        __syncthreads();
        #pragma unroll
        for (int k = 0; k < 16; k++) {
            float4 av = *(const float4*)&As[k][ty * 4];
            float4 bv = *(const float4*)&Bs[k][tx * 4];
            float a_[4] = {av.x, av.y, av.z, av.w};
            float b_[4] = {bv.x, bv.y, bv.z, bv.w};
            #pragma unroll
            for (int r = 0; r < 4; r++)
                #pragma unroll
                for (int cc = 0; cc < 4; cc++)
                    acc[r][cc] += a_[r] * b_[cc];
        }
        __syncthreads();
    }
    const float* seg = segments + (size_t)b * LQ * 2;
    #pragma unroll
    for (int r = 0; r < 4; r++) {
        int i = i0 + ty * 4 + r;
        float ci = seg[i * 2], li = seg[i * 2 + 1];
        float si = ci - li * 0.5f, ei = ci + li * 0.5f;
        unsigned int pack = 0;
        #pragma unroll
        for (int cc = 0; cc < 4; cc++) {
            int j = j0 + tx * 4 + cc;
            float cj = seg[j * 2], lj = seg[j * 2 + 1];
            float sj = cj - lj * 0.5f, ej = cj + lj * 0.5f;
            float inter = fmaxf(fminf(ei, ej) - fmaxf(si, sj), 0.0f);
            float uni   = li + lj - inter;
            float iou   = inter / uni;
            bool adj = ((iou <= IOU_THR) || (i == j)) && (acc[r][cc] > COS_THR);
            unsigned int m = adj ? 0u : 1u;   // 1 = masked
            pack |= m << (8 * cc);
        }
        *(unsigned int*)&mask[((size_t)b * LQ + i) * LQ + j0 + tx * 4] = pack;
    }
}

// ---------------------------------------------------------------------------
// Kernel 4: QKV bf16 MFMA GEMM. C = hb @ W^T + bias.
// Outputs: Qb/Kb in [b][h][i][dh], Vt in [b][h][dh][i] (all bf16)
// ---------------------------------------------------------------------------
__global__ __launch_bounds__(256) void qkv_kernel(const unsigned short* __restrict__ hb,
                                                  const unsigned short* __restrict__ Wb,
                                                  const float* __restrict__ bq,
                                                  const float* __restrict__ bk,
                                                  const float* __restrict__ bv,
                                                  unsigned short* __restrict__ Qb,
                                                  unsigned short* __restrict__ Kb,
                                                  unsigned short* __restrict__ Vt) {
    int z = blockIdx.z;
    const unsigned short* W = Wb + (size_t)z * D * D;
    const float* bias = (z == 0) ? bq : (z == 1) ? bk : bv;
    int tid = threadIdx.x;
    int w = tid >> 6, lane = tid & 63;
    int c = lane & 15, q4 = lane >> 4;
    int m0 = blockIdx.x * 64 + w * 16;
    int n0 = blockIdx.y * 64;
    f32x4 acc[4] = {};
    const unsigned short* arow = hb + (size_t)(m0 + c) * D;
    for (int k0 = 0; k0 < D; k0 += 32) {
        bf16x8 af = *(const bf16x8*)(arow + k0 + q4 * 8);
        #pragma unroll
        for (int cb = 0; cb < 4; cb++) {
            bf16x8 bfr = *(const bf16x8*)(W + (size_t)(n0 + cb * 16 + c) * D + k0 + q4 * 8);
            acc[cb] = __builtin_amdgcn_mfma_f32_16x16x32_bf16(af, bfr, acc[cb], 0, 0, 0);
        }
    }
    // C-layout: row = m0 + q4*4 + r, col = n0 + cb*16 + c
    #pragma unroll
    for (int r = 0; r < 4; r++) {
        int mm = m0 + q4 * 4 + r;
        int b = mm >> 10, i = mm & 1023;
        #pragma unroll
        for (int cb = 0; cb < 4; cb++) {
            int n = n0 + cb * 16 + c;
            unsigned short val = f2bf(acc[cb][r] + bias[n]);
            int hh = n >> 6, dh = n & 63;
            size_t bh = (size_t)b * NH + hh;
            if (z == 2)
                Vt[(bh * DH + dh) * LQ + i] = val;
            else {
                unsigned short* dst = (z == 0) ? Qb : Kb;
                dst[(bh * LQ + i) * DH + dh] = val;
            }
        }
    }
}

// ---------------------------------------------------------------------------
// Kernel 5: flash-style MFMA attention + residual + transpose-out
// Block: 256 thr (4 waves), each wave owns 16 Q-rows. Grid: (LQ/64, NH, BZ)
// ---------------------------------------------------------------------------
__global__ __launch_bounds__(256) void attn_kernel(const unsigned short* __restrict__ Qb,
                                                   const unsigned short* __restrict__ Kb,
                                                   const unsigned short* __restrict__ Vt,
                                                   const unsigned char* __restrict__ mask,
                                                   const float* __restrict__ h,
                                                   float* __restrict__ out) {
    int tid = threadIdx.x;
    int w = tid >> 6, lane = tid & 63;
    int c = lane & 15, q4 = lane >> 4;
    int hh = blockIdx.y, b = blockIdx.z;
    int i0 = blockIdx.x * 64 + w * 16;       // wave's Q-row base
    size_t bh = (size_t)b * NH + hh;

    __shared__ unsigned short p_lds[4][16][72];  // per-wave P tile, [m][k], pad 72

    // Q A-frags (m = c, k = q4*8 + t + s*32)
    const unsigned short* Qrow = Qb + (bh * LQ + i0 + c) * DH;
    bf16x8 qa0 = *(const bf16x8*)(Qrow + q4 * 8);
    bf16x8 qa1 = *(const bf16x8*)(Qrow + 32 + q4 * 8);

    f32x4 O[4] = {};
    float m_r[4] = {NEG, NEG, NEG, NEG};
    float l_r[4] = {0.f, 0.f, 0.f, 0.f};

    const unsigned short* Kbase = Kb + bh * LQ * DH;
    const unsigned short* Vbase = Vt + bh * DH * LQ;
    const unsigned char*  mbase = mask + ((size_t)b * LQ + i0) * LQ;

    for (int j0 = 0; j0 < LQ; j0 += 64) {
        // ---- S = Q @ K^T (16 x 64) ----
        f32x4 S[4] = {};
        #pragma unroll
        for (int cb = 0; cb < 4; cb++) {
            const unsigned short* krow = Kbase + (size_t)(j0 + cb * 16 + c) * DH;
            bf16x8 kf0 = *(const bf16x8*)(krow + q4 * 8);
            bf16x8 kf1 = *(const bf16x8*)(krow + 32 + q4 * 8);
            S[cb] = __builtin_amdgcn_mfma_f32_16x16x32_bf16(qa0, kf0, S[cb], 0, 0, 0);
            S[cb] = __builtin_amdgcn_mfma_f32_16x16x32_bf16(qa1, kf1, S[cb], 0, 0, 0);
        }
        // ---- scale + mask + tile row-max ----
        float p[4][4];                         // [cb][r]
        float tmax[4] = {NEG, NEG, NEG, NEG};
        #pragma unroll
        for (int cb = 0; cb < 4; cb++) {
            #pragma unroll
            for (int r = 0; r < 4; r++) {
                float sc = S[cb][r] * 0.125f;
                unsigned char mm = mbase[(size_t)(q4 * 4 + r) * LQ + j0 + cb * 16 + c];
                sc = mm ? NEG : sc;
                p[cb][r] = sc;
                tmax[r] = fmaxf(tmax[r], sc);
            }
        }
        #pragma unroll
        for (int r = 0; r < 4; r++) {
            float v = tmax[r];
            v = fmaxf(v, __shfl_xor(v, 1));
            v = fmaxf(v, __shfl_xor(v, 2));
            v = fmaxf(v, __shfl_xor(v, 4));
            v = fmaxf(v, __shfl_xor(v, 8));
            tmax[r] = v;
        }
        // ---- online softmax update ----
        float rsum[4];
        #pragma unroll
        for (int r = 0; r < 4; r++) {
            float mn = fmaxf(m_r[r], tmax[r]);
            float alpha = __expf(m_r[r] - mn);
            m_r[r] = mn;
            l_r[r] *= alpha;
            #pragma unroll
            for (int cb2 = 0; cb2 < 4; cb2++) O[cb2][r] *= alpha;
            float s0 = 0.f;
            #pragma unroll
            for (int cb = 0; cb < 4; cb++) {
                float e = __expf(p[cb][r] - mn);
                p[cb][r] = e;
                s0 += e;
            }
            rsum[r] = s0;
        }
        #pragma unroll
        for (int r = 0; r < 4; r++) {
            float v = rsum[r];
            v += __shfl_xor(v, 1);
            v += __shfl_xor(v, 2);
            v += __shfl_xor(v, 4);
            v += __shfl_xor(v, 8);
            l_r[r] += v;
        }
        // ---- P: C-layout -> LDS -> A-layout ----
        #pragma unroll
        for (int cb = 0; cb < 4; cb++)
            #pragma unroll
            for (int r = 0; r < 4; r++)
                p_lds[w][q4 * 4 + r][cb * 16 + c] = f2bf(p[cb][r]);
        __syncthreads();
        // ---- O += P @ V ----
        #pragma unroll
        for (int s = 0; s < 2; s++) {
            bf16x8 pf = *(const bf16x8*)&p_lds[w][c][s * 32 + q4 * 8];
            #pragma unroll
            for (int cb = 0; cb < 4; cb++) {
                bf16x8 vf = *(const bf16x8*)(Vbase + (size_t)(cb * 16 + c) * LQ + j0 + s * 32 + q4 * 8);
                O[cb] = __builtin_amdgcn_mfma_f32_16x16x32_bf16(pf, vf, O[cb], 0, 0, 0);
            }
        }
        __syncthreads();
    }
    // ---- epilogue: /l, +h, transpose to [i][b][d] ----
    #pragma unroll
    for (int r = 0; r < 4; r++) {
        int i = i0 + q4 * 4 + r;
        float inv = 1.0f / l_r[r];
        #pragma unroll
        for (int cb = 0; cb < 4; cb++) {
            int col = hh * 64 + cb * 16 + c;
            float val = O[cb][r] * inv + h[((size_t)b * LQ + i) * D + col];
            out[((size_t)i * BZ + b) * D + col] = val;
        }
    }
}

// ---------------------------------------------------------------------------
extern "C" void kernel_launch(void* const* d_in, const int* in_sizes, int n_in,
                              void* d_out, int out_size, void* d_ws, size_t ws_size,
                              hipStream_t stream) {
    const float* query    = (const float*)d_in[0];
    const float* segments = (const float*)d_in[1];
    const float* Wq = (const float*)d_in[2];
    const float* bq = (const float*)d_in[3];
    const float* Wk = (const float*)d_in[4];
    const float* bk = (const float*)d_in[5];
    const float* Wv = (const float*)d_in[6];
    const float* bv = (const float*)d_in[7];
    float* out = (float*)d_out;

    const size_t NTOK = (size_t)BZ * LQ;           // 8192
    char* ws = (char*)d_ws;
    float*          h     = (float*)ws;            ws += NTOK * D * 4;      // 16 MB
    unsigned short* hbuf  = (unsigned short*)ws;   ws += NTOK * D * 2;      // 8 MB
    unsigned short* Qb    = (unsigned short*)ws;   ws += NTOK * D * 2;      // 8 MB
    unsigned short* Kb    = (unsigned short*)ws;   ws += NTOK * D * 2;      // 8 MB
    unsigned short* Vt    = (unsigned short*)ws;   ws += NTOK * D * 2;      // 8 MB
    unsigned short* Wb    = (unsigned short*)ws;   ws += (size_t)3 * D * D * 2; // 1.5 MB
    float*          rnorm = (float*)ws;            ws += NTOK * 4;          // 32 KB
    unsigned char*  mask  = (unsigned char*)ws;    /* 8 MB */

    prep_kernel<<<NTOK, 256, 0, stream>>>(query, h, hbuf, rnorm);
    cvt_w_kernel<<<3 * D * D / 4 / 256, 256, 0, stream>>>(Wq, Wk, Wv, Wb);
    mask_kernel<<<dim3(LQ / 64, LQ / 64, BZ), 256, 0, stream>>>(h, rnorm, segments, mask);
    qkv_kernel<<<dim3(NTOK / 64, D / 64, 3), 256, 0, stream>>>(hbuf, Wb, bq, bk, bv, Qb, Kb, Vt);
    attn_kernel<<<dim3(LQ / 64, NH, BZ), 256, 0, stream>>>(Qb, Kb, Vt, mask, h, out);
}

// Round 3
// 197.309 us; speedup vs baseline: 20.5345x; 2.4231x over previous
//
#include <hip/hip_runtime.h>
#include <math.h>

#define LQ 1024
#define BZ 8
#define D  512
#define NH 8
#define DH 64
#define IOU_THR 0.2f
#define COS_THR 0.2f
#define NEG (-1e30f)

typedef short bf16x8 __attribute__((ext_vector_type(8)));
typedef float f32x4  __attribute__((ext_vector_type(4)));

#define MFMA16(a, b, cacc) __builtin_amdgcn_mfma_f32_16x16x32_bf16(a, b, cacc, 0, 0, 0)

__device__ inline unsigned short f2bf(float x) {
    union { float f; unsigned int u; } v; v.f = x;
    unsigned int r = v.u + 0x7FFF + ((v.u >> 16) & 1);
    return (unsigned short)(r >> 16);
}
__device__ inline float bf2f(unsigned short b) {
    union { unsigned int u; float f; } v; v.u = ((unsigned int)b) << 16;
    return v.f;
}

// async global->LDS, 16B per lane. ldsbase must be wave-uniform; HW adds lane*16.
__device__ __forceinline__ void gll16(const void* g, void* ldsbase) {
    __builtin_amdgcn_global_load_lds(
        (const __attribute__((address_space(1))) unsigned int*)g,
        (__attribute__((address_space(3))) unsigned int*)ldsbase, 16, 0, 0);
}

// ---------------------------------------------------------------------------
// Kernel 1: transpose query -> h (fp32); hi/lo bf16 split of h; rnorm
// ---------------------------------------------------------------------------
__global__ __launch_bounds__(256) void prep_kernel(const float* __restrict__ query,
                                                   float* __restrict__ h,
                                                   unsigned short* __restrict__ hi,
                                                   unsigned short* __restrict__ lo,
                                                   float* __restrict__ rnorm) {
    int blk = blockIdx.x;            // b*LQ + i
    int b = blk >> 10, i = blk & 1023;
    const float* src = query + ((size_t)i * BZ + b) * D;
    int tid = threadIdx.x;
    float2 v = ((const float2*)src)[tid];
    ((float2*)(h + (size_t)blk * D))[tid] = v;
    unsigned short hx = f2bf(v.x), hy = f2bf(v.y);
    ((unsigned int*)(hi + (size_t)blk * D))[tid] = (unsigned int)hx | ((unsigned int)hy << 16);
    unsigned short lx = f2bf(v.x - bf2f(hx)), ly = f2bf(v.y - bf2f(hy));
    ((unsigned int*)(lo + (size_t)blk * D))[tid] = (unsigned int)lx | ((unsigned int)ly << 16);
    float ss = v.x * v.x + v.y * v.y;
    __shared__ float red[256];
    red[tid] = ss; __syncthreads();
    for (int s = 128; s > 0; s >>= 1) {
        if (tid < s) red[tid] += red[tid + s];
        __syncthreads();
    }
    if (tid == 0) rnorm[blk] = 1.0f / fmaxf(sqrtf(red[0]), 1e-8f);
}

// ---------------------------------------------------------------------------
// Kernel 2: Wq/Wk/Wv fp32 -> bf16
// ---------------------------------------------------------------------------
__global__ __launch_bounds__(256) void cvt_w_kernel(const float* __restrict__ Wq,
                                                    const float* __restrict__ Wk,
                                                    const float* __restrict__ Wv,
                                                    unsigned short* __restrict__ Wb) {
    int t = blockIdx.x * 256 + threadIdx.x;
    int mat = t >> 16;
    int off = (t & 65535) * 4;
    const float* src = (mat == 0) ? Wq : (mat == 1) ? Wk : Wv;
    float4 v = *(const float4*)(src + off);
    uint2 p;
    p.x = (unsigned int)f2bf(v.x) | ((unsigned int)f2bf(v.y) << 16);
    p.y = (unsigned int)f2bf(v.z) | ((unsigned int)f2bf(v.w) << 16);
    *(uint2*)(Wb + (size_t)mat * D * D + off) = p;
}

// ---------------------------------------------------------------------------
// Kernel 3: mask via split-bf16 MFMA (hi*hi + hi*lo + lo*hi), fp64 fixup near
// threshold; emits mask bytes + per-(16x64)-tile "any unmasked" summary.
// 128x128 tile, 4 waves in 2x2, BK=32, global_load_lds staging.
// ---------------------------------------------------------------------------
__global__ __launch_bounds__(256) void mask_kernel(const unsigned short* __restrict__ hi,
                                                   const unsigned short* __restrict__ lo,
                                                   const float* __restrict__ h,
                                                   const float* __restrict__ rnorm,
                                                   const float* __restrict__ segments,
                                                   unsigned char* __restrict__ mask,
                                                   unsigned char* __restrict__ summ) {
    __shared__ short Ah[128 * 32], Al[128 * 32], Bh[128 * 32], Bl[128 * 32];
    __shared__ int summ_lds[8][2];
    int b = blockIdx.z, i0 = blockIdx.y * 128, j0 = blockIdx.x * 128;
    int tid = threadIdx.x, w = tid >> 6, lane = tid & 63;
    int c = lane & 15, q4 = lane >> 4;
    int wr = w >> 1, wc = w & 1;
    if (tid < 16) summ_lds[tid >> 1][tid & 1] = 0;

    f32x4 acc[4][4] = {};
    const char* Asrc_h = (const char*)(hi + ((size_t)b * LQ + i0) * D);
    const char* Asrc_l = (const char*)(lo + ((size_t)b * LQ + i0) * D);
    const char* Bsrc_h = (const char*)(hi + ((size_t)b * LQ + j0) * D);
    const char* Bsrc_l = (const char*)(lo + ((size_t)b * LQ + j0) * D);

    int ch0 = 2 * w;                       // this wave stages chunks ch0, ch0+1 of each tile
    int o0 = ch0 * 1024 + lane * 16;       // byte offset within tile (for global addr)
    int o1 = o0 + 1024;
    size_t g0 = (size_t)(o0 >> 6) * 1024 + (size_t)(o0 & 63);
    size_t g1 = (size_t)(o1 >> 6) * 1024 + (size_t)(o1 & 63);

    for (int k0 = 0; k0 < D; k0 += 32) {
        size_t kb = (size_t)k0 * 2;
        gll16(Asrc_h + kb + g0, (char*)Ah + ch0 * 1024);
        gll16(Asrc_h + kb + g1, (char*)Ah + ch0 * 1024 + 1024);
        gll16(Asrc_l + kb + g0, (char*)Al + ch0 * 1024);
        gll16(Asrc_l + kb + g1, (char*)Al + ch0 * 1024 + 1024);
        gll16(Bsrc_h + kb + g0, (char*)Bh + ch0 * 1024);
        gll16(Bsrc_h + kb + g1, (char*)Bh + ch0 * 1024 + 1024);
        gll16(Bsrc_l + kb + g0, (char*)Bl + ch0 * 1024);
        gll16(Bsrc_l + kb + g1, (char*)Bl + ch0 * 1024 + 1024);
        __syncthreads();
        bf16x8 ah[4], al[4], bh[4], bl[4];
        #pragma unroll
        for (int f = 0; f < 4; f++) {
            ah[f] = *(const bf16x8*)&Ah[(wr * 64 + f * 16 + c) * 32 + q4 * 8];
            al[f] = *(const bf16x8*)&Al[(wr * 64 + f * 16 + c) * 32 + q4 * 8];
            bh[f] = *(const bf16x8*)&Bh[(wc * 64 + f * 16 + c) * 32 + q4 * 8];
            bl[f] = *(const bf16x8*)&Bl[(wc * 64 + f * 16 + c) * 32 + q4 * 8];
        }
        #pragma unroll
        for (int fr = 0; fr < 4; fr++)
            #pragma unroll
            for (int fc = 0; fc < 4; fc++) {
                acc[fr][fc] = MFMA16(ah[fr], bh[fc], acc[fr][fc]);
                acc[fr][fc] = MFMA16(ah[fr], bl[fc], acc[fr][fc]);
                acc[fr][fc] = MFMA16(al[fr], bh[fc], acc[fr][fc]);
            }
        __syncthreads();
    }

    const float* rn  = rnorm + b * LQ;
    const float* seg = segments + (size_t)b * LQ * 2;
    unsigned char* mbase = mask + ((size_t)b << 20);
    #pragma unroll
    for (int fr = 0; fr < 4; fr++) {
        int anyun = 0;
        #pragma unroll
        for (int r = 0; r < 4; r++) {
            int i = i0 + wr * 64 + fr * 16 + q4 * 4 + r;
            float rni = rn[i];
            float ci = seg[i * 2], li = seg[i * 2 + 1];
            float si = ci - li * 0.5f, ei = ci + li * 0.5f;
            #pragma unroll
            for (int fc = 0; fc < 4; fc++) {
                int j = j0 + wc * 64 + fc * 16 + c;
                float rnj = rn[j];
                float cosv = acc[fr][fc][r] * rni * rnj;
                if (fabsf(cosv - COS_THR) < 1e-3f) {   // exact recompute (rare)
                    const float* hri = h + ((size_t)b * LQ + i) * D;
                    const float* hrj = h + ((size_t)b * LQ + j) * D;
                    double dd = 0.0;
                    for (int k = 0; k < D; k++) dd += (double)hri[k] * (double)hrj[k];
                    cosv = (float)(dd * (double)rni * (double)rnj);
                }
                float cj = seg[j * 2], lj = seg[j * 2 + 1];
                float sj = cj - lj * 0.5f, ej = cj + lj * 0.5f;
                float inter = fmaxf(fminf(ei, ej) - fmaxf(si, sj), 0.0f);
                float uni   = li + lj - inter;
                float iou   = inter / uni;
                bool adj = ((iou <= IOU_THR) || (i == j)) && (cosv > COS_THR);
                mbase[(size_t)i * LQ + j] = adj ? 0 : 1;   // 1 = masked
                anyun |= adj ? 1 : 0;
            }
        }
        if (anyun) atomicOr(&summ_lds[wr * 4 + fr][wc], 1);
    }
    __syncthreads();
    if (tid < 16) {
        int lit = tid >> 1, ljt = tid & 1;
        summ[((size_t)b * 64 + (i0 >> 4) + lit) * 16 + (j0 >> 6) + ljt] =
            summ_lds[lit][ljt] ? 1 : 0;
    }
}

// ---------------------------------------------------------------------------
// Kernel 4: QKV bf16 MFMA GEMM, m97-style staged 128x128 tile.
// Outputs: Qb/Kb [b][h][i][dh], Vt [b][h][dh][i]
// ---------------------------------------------------------------------------
__global__ __launch_bounds__(256) void qkv_kernel(const unsigned short* __restrict__ hb,
                                                  const unsigned short* __restrict__ Wb,
                                                  const float* __restrict__ bq,
                                                  const float* __restrict__ bk,
                                                  const float* __restrict__ bv,
                                                  unsigned short* __restrict__ Qb,
                                                  unsigned short* __restrict__ Kb,
                                                  unsigned short* __restrict__ Vt) {
    __shared__ short As[128 * 32], Bs[128 * 32];
    int z = blockIdx.z;
    const unsigned short* W = Wb + (size_t)z * D * D;
    const float* bias = (z == 0) ? bq : (z == 1) ? bk : bv;
    int m0 = blockIdx.x * 128, n0 = blockIdx.y * 128;
    int tid = threadIdx.x, w = tid >> 6, lane = tid & 63;
    int c = lane & 15, q4 = lane >> 4;
    int wr = w >> 1, wc = w & 1;

    f32x4 acc[4][4] = {};
    const char* Asrc = (const char*)(hb + (size_t)m0 * D);
    const char* Bsrc = (const char*)(W + (size_t)n0 * D);
    int ch0 = 2 * w;
    int o0 = ch0 * 1024 + lane * 16;
    int o1 = o0 + 1024;
    size_t g0 = (size_t)(o0 >> 6) * 1024 + (size_t)(o0 & 63);
    size_t g1 = (size_t)(o1 >> 6) * 1024 + (size_t)(o1 & 63);

    for (int k0 = 0; k0 < D; k0 += 32) {
        size_t kb = (size_t)k0 * 2;
        gll16(Asrc + kb + g0, (char*)As + ch0 * 1024);
        gll16(Asrc + kb + g1, (char*)As + ch0 * 1024 + 1024);
        gll16(Bsrc + kb + g0, (char*)Bs + ch0 * 1024);
        gll16(Bsrc + kb + g1, (char*)Bs + ch0 * 1024 + 1024);
        __syncthreads();
        bf16x8 af[4], bf[4];
        #pragma unroll
        for (int f = 0; f < 4; f++) {
            af[f] = *(const bf16x8*)&As[(wr * 64 + f * 16 + c) * 32 + q4 * 8];
            bf[f] = *(const bf16x8*)&Bs[(wc * 64 + f * 16 + c) * 32 + q4 * 8];
        }
        #pragma unroll
        for (int fr = 0; fr < 4; fr++)
            #pragma unroll
            for (int fc = 0; fc < 4; fc++)
                acc[fr][fc] = MFMA16(af[fr], bf[fc], acc[fr][fc]);
        __syncthreads();
    }

    #pragma unroll
    for (int fr = 0; fr < 4; fr++)
        #pragma unroll
        for (int r = 0; r < 4; r++) {
            int m = m0 + wr * 64 + fr * 16 + q4 * 4 + r;
            int b = m >> 10, i = m & 1023;
            #pragma unroll
            for (int fc = 0; fc < 4; fc++) {
                int n = n0 + wc * 64 + fc * 16 + c;
                unsigned short us = f2bf(acc[fr][fc][r] + bias[n]);
                int hh = n >> 6, dh = n & 63;
                size_t bh = (size_t)b * NH + hh;
                if (z == 2)
                    Vt[(bh * DH + dh) * LQ + i] = us;
                else {
                    unsigned short* dst = (z == 0) ? Qb : Kb;
                    dst[(bh * LQ + i) * DH + dh] = us;
                }
            }
        }
}

// ---------------------------------------------------------------------------
// Kernel 5: flash MFMA attention with summary-driven tile skipping.
// 4 waves/block, wave owns 16 Q-rows; no block barriers (per-wave LDS only).
// ---------------------------------------------------------------------------
__global__ __launch_bounds__(256) void attn_kernel(const unsigned short* __restrict__ Qb,
                                                   const unsigned short* __restrict__ Kb,
                                                   const unsigned short* __restrict__ Vt,
                                                   const unsigned char* __restrict__ mask,
                                                   const unsigned char* __restrict__ summ,
                                                   const float* __restrict__ h,
                                                   float* __restrict__ out) {
    int tid = threadIdx.x;
    int w = tid >> 6, lane = tid & 63;
    int c = lane & 15, q4 = lane >> 4;
    int hh = blockIdx.y, b = blockIdx.z;
    int i0 = blockIdx.x * 64 + w * 16;
    size_t bh = (size_t)b * NH + hh;

    __shared__ unsigned short p_lds[4][16][72];

    const unsigned short* Qrow = Qb + (bh * LQ + i0 + c) * DH;
    bf16x8 qa0 = *(const bf16x8*)(Qrow + q4 * 8);
    bf16x8 qa1 = *(const bf16x8*)(Qrow + 32 + q4 * 8);

    f32x4 O[4] = {};
    float m_r[4] = {NEG, NEG, NEG, NEG};
    float l_r[4] = {0.f, 0.f, 0.f, 0.f};

    const unsigned short* Kbase = Kb + bh * LQ * DH;
    const unsigned short* Vbase = Vt + bh * DH * LQ;
    const unsigned char*  mbase = mask + ((size_t)b * LQ + i0) * LQ;
    const unsigned char*  srow  = summ + ((size_t)b * 64 + (i0 >> 4)) * 16;

    for (int jt = 0; jt < 16; jt++) {
        if (!srow[jt]) continue;           // fully-masked tile: contributes nothing
        int j0 = jt * 64;
        f32x4 S[4] = {};
        #pragma unroll
        for (int cb = 0; cb < 4; cb++) {
            const unsigned short* krow = Kbase + (size_t)(j0 + cb * 16 + c) * DH;
            bf16x8 kf0 = *(const bf16x8*)(krow + q4 * 8);
            bf16x8 kf1 = *(const bf16x8*)(krow + 32 + q4 * 8);
            S[cb] = MFMA16(qa0, kf0, S[cb]);
            S[cb] = MFMA16(qa1, kf1, S[cb]);
        }
        float p[4][4];
        float tmax[4] = {NEG, NEG, NEG, NEG};
        #pragma unroll
        for (int cb = 0; cb < 4; cb++)
            #pragma unroll
            for (int r = 0; r < 4; r++) {
                float sc = S[cb][r] * 0.125f;
                unsigned char mm = mbase[(size_t)(q4 * 4 + r) * LQ + j0 + cb * 16 + c];
                sc = mm ? NEG : sc;
                p[cb][r] = sc;
                tmax[r] = fmaxf(tmax[r], sc);
            }
        #pragma unroll
        for (int r = 0; r < 4; r++) {
            float v = tmax[r];
            v = fmaxf(v, __shfl_xor(v, 1));
            v = fmaxf(v, __shfl_xor(v, 2));
            v = fmaxf(v, __shfl_xor(v, 4));
            v = fmaxf(v, __shfl_xor(v, 8));
            tmax[r] = v;
        }
        float rsum[4];
        #pragma unroll
        for (int r = 0; r < 4; r++) {
            float mn = fmaxf(m_r[r], tmax[r]);
            float alpha = __expf(m_r[r] - mn);
            m_r[r] = mn;
            l_r[r] *= alpha;
            #pragma unroll
            for (int cb2 = 0; cb2 < 4; cb2++) O[cb2][r] *= alpha;
            float s0 = 0.f;
            #pragma unroll
            for (int cb = 0; cb < 4; cb++) {
                float e = __expf(p[cb][r] - mn);
                p[cb][r] = e;
                s0 += e;
            }
            rsum[r] = s0;
        }
        #pragma unroll
        for (int r = 0; r < 4; r++) {
            float v = rsum[r];
            v += __shfl_xor(v, 1);
            v += __shfl_xor(v, 2);
            v += __shfl_xor(v, 4);
            v += __shfl_xor(v, 8);
            l_r[r] += v;
        }
        #pragma unroll
        for (int cb = 0; cb < 4; cb++)
            #pragma unroll
            for (int r = 0; r < 4; r++)
                p_lds[w][q4 * 4 + r][cb * 16 + c] = f2bf(p[cb][r]);
        // per-wave LDS: wave-internal lgkmcnt ordering suffices, no barrier
        #pragma unroll
        for (int s = 0; s < 2; s++) {
            bf16x8 pf = *(const bf16x8*)&p_lds[w][c][s * 32 + q4 * 8];
            #pragma unroll
            for (int cb = 0; cb < 4; cb++) {
                bf16x8 vf = *(const bf16x8*)(Vbase + (size_t)(cb * 16 + c) * LQ + j0 + s * 32 + q4 * 8);
                O[cb] = MFMA16(pf, vf, O[cb]);
            }
        }
    }
    #pragma unroll
    for (int r = 0; r < 4; r++) {
        int i = i0 + q4 * 4 + r;
        float inv = 1.0f / l_r[r];
        #pragma unroll
        for (int cb = 0; cb < 4; cb++) {
            int col = hh * 64 + cb * 16 + c;
            float val = O[cb][r] * inv + h[((size_t)b * LQ + i) * D + col];
            out[((size_t)i * BZ + b) * D + col] = val;
        }
    }
}

// ---------------------------------------------------------------------------
extern "C" void kernel_launch(void* const* d_in, const int* in_sizes, int n_in,
                              void* d_out, int out_size, void* d_ws, size_t ws_size,
                              hipStream_t stream) {
    const float* query    = (const float*)d_in[0];
    const float* segments = (const float*)d_in[1];
    const float* Wq = (const float*)d_in[2];
    const float* bq = (const float*)d_in[3];
    const float* Wk = (const float*)d_in[4];
    const float* bk = (const float*)d_in[5];
    const float* Wv = (const float*)d_in[6];
    const float* bv = (const float*)d_in[7];
    float* out = (float*)d_out;

    const size_t NTOK = (size_t)BZ * LQ;
    char* ws = (char*)d_ws;
    float*          h     = (float*)ws;            ws += NTOK * D * 4;          // 16 MB
    unsigned short* hbuf  = (unsigned short*)ws;   ws += NTOK * D * 2;          // 8 MB (hi)
    unsigned short* hlo   = (unsigned short*)ws;   ws += NTOK * D * 2;          // 8 MB (lo)
    unsigned short* Qb    = (unsigned short*)ws;   ws += NTOK * D * 2;          // 8 MB
    unsigned short* Kb    = (unsigned short*)ws;   ws += NTOK * D * 2;          // 8 MB
    unsigned short* Vt    = (unsigned short*)ws;   ws += NTOK * D * 2;          // 8 MB
    unsigned short* Wb    = (unsigned short*)ws;   ws += (size_t)3 * D * D * 2; // 1.5 MB
    float*          rnorm = (float*)ws;            ws += NTOK * 4;              // 32 KB
    unsigned char*  mask  = (unsigned char*)ws;    ws += (size_t)BZ * LQ * LQ;  // 8 MB
    unsigned char*  summ  = (unsigned char*)ws;    /* 8 KB: [b][it(64)][jt(16)] */

    prep_kernel<<<NTOK, 256, 0, stream>>>(query, h, hbuf, hlo, rnorm);
    cvt_w_kernel<<<3 * D * D / 4 / 256, 256, 0, stream>>>(Wq, Wk, Wv, Wb);
    mask_kernel<<<dim3(LQ / 128, LQ / 128, BZ), 256, 0, stream>>>(hbuf, hlo, h, rnorm,
                                                                  segments, mask, summ);
    qkv_kernel<<<dim3(NTOK / 128, D / 128, 3), 256, 0, stream>>>(hbuf, Wb, bq, bk, bv,
                                                                 Qb, Kb, Vt);
    attn_kernel<<<dim3(LQ / 64, NH, BZ), 256, 0, stream>>>(Qb, Kb, Vt, mask, summ, h, out);
}

// Round 4
// 186.842 us; speedup vs baseline: 21.6848x; 1.0560x over previous
//
#include <hip/hip_runtime.h>
#include <math.h>

#define LQ 1024
#define BZ 8
#define D  512
#define NH 8
#define DH 64
#define IOU_THR 0.2f
#define COS_THR 0.2f
#define NEG (-1e30f)

typedef short bf16x8 __attribute__((ext_vector_type(8)));
typedef float f32x4  __attribute__((ext_vector_type(4)));

#define MFMA16(a, b, cacc) __builtin_amdgcn_mfma_f32_16x16x32_bf16(a, b, cacc, 0, 0, 0)

__device__ inline unsigned short f2bf(float x) {
    union { float f; unsigned int u; } v; v.f = x;
    unsigned int r = v.u + 0x7FFF + ((v.u >> 16) & 1);
    return (unsigned short)(r >> 16);
}
__device__ inline float bf2f(unsigned short b) {
    union { unsigned int u; float f; } v; v.u = ((unsigned int)b) << 16;
    return v.f;
}

// async global->LDS, 16B per lane. LDS base wave-uniform; HW adds lane*16.
__device__ __forceinline__ void gll16(const void* g, void* ldsbase) {
    __builtin_amdgcn_global_load_lds(
        (const __attribute__((address_space(1))) unsigned int*)g,
        (__attribute__((address_space(3))) unsigned int*)ldsbase, 16, 0, 0);
}

// ---------------------------------------------------------------------------
// Kernel 1: transpose query -> h (fp32) + hi (bf16); rnorm
// ---------------------------------------------------------------------------
__global__ __launch_bounds__(256) void prep_kernel(const float* __restrict__ query,
                                                   float* __restrict__ h,
                                                   unsigned short* __restrict__ hi,
                                                   float* __restrict__ rnorm) {
    int blk = blockIdx.x;            // b*LQ + i
    int b = blk >> 10, i = blk & 1023;
    const float* src = query + ((size_t)i * BZ + b) * D;
    int tid = threadIdx.x;
    float2 v = ((const float2*)src)[tid];
    ((float2*)(h + (size_t)blk * D))[tid] = v;
    unsigned short hx = f2bf(v.x), hy = f2bf(v.y);
    ((unsigned int*)(hi + (size_t)blk * D))[tid] = (unsigned int)hx | ((unsigned int)hy << 16);
    float ss = v.x * v.x + v.y * v.y;
    __shared__ float red[256];
    red[tid] = ss; __syncthreads();
    for (int s = 128; s > 0; s >>= 1) {
        if (tid < s) red[tid] += red[tid + s];
        __syncthreads();
    }
    if (tid == 0) rnorm[blk] = 1.0f / fmaxf(sqrtf(red[0]), 1e-8f);
}

// ---------------------------------------------------------------------------
// Kernel 2: Wq/Wk/Wv fp32 -> bf16
// ---------------------------------------------------------------------------
__global__ __launch_bounds__(256) void cvt_w_kernel(const float* __restrict__ Wq,
                                                    const float* __restrict__ Wk,
                                                    const float* __restrict__ Wv,
                                                    unsigned short* __restrict__ Wb) {
    int t = blockIdx.x * 256 + threadIdx.x;
    int mat = t >> 16;
    int off = (t & 65535) * 4;
    const float* src = (mat == 0) ? Wq : (mat == 1) ? Wk : Wv;
    float4 v = *(const float4*)(src + off);
    uint2 p;
    p.x = (unsigned int)f2bf(v.x) | ((unsigned int)f2bf(v.y) << 16);
    p.y = (unsigned int)f2bf(v.z) | ((unsigned int)f2bf(v.w) << 16);
    *(uint2*)(Wb + (size_t)mat * D * D + off) = p;
}

// ---------------------------------------------------------------------------
// Kernel 3: mask via hi-only bf16 MFMA; fp64 fixup for |cos-0.2| < 3e-3.
// 128x128 tile, BK=64, XOR-swizzled gll16 staging (conflict-free ds_read).
// Emits mask bytes + per-(16x64)-tile "any unmasked" summary.
// ---------------------------------------------------------------------------
__global__ __launch_bounds__(256) void mask_kernel(const unsigned short* __restrict__ hi,
                                                   const float* __restrict__ h,
                                                   const float* __restrict__ rnorm,
                                                   const float* __restrict__ segments,
                                                   unsigned char* __restrict__ mask,
                                                   unsigned char* __restrict__ summ) {
    __shared__ short As[128 * 64], Bs[128 * 64];   // 16 KB each
    __shared__ int summ_lds[8][2];
    int b = blockIdx.z, i0 = blockIdx.y * 128, j0 = blockIdx.x * 128;
    int tid = threadIdx.x, w = tid >> 6, lane = tid & 63;
    int c = lane & 15, q4 = lane >> 4;
    int wr = w >> 1, wc = w & 1;
    if (tid < 16) summ_lds[tid >> 1][tid & 1] = 0;

    f32x4 acc[4][4] = {};
    const char* Asrc = (const char*)(hi + ((size_t)b * LQ + i0) * D);
    const char* Bsrc = (const char*)(hi + ((size_t)b * LQ + j0) * D);

    // staging geometry: chunk n (1 KB) = rows 8n..8n+7, k-slice 64 shorts (128 B)
    // lane L -> row 8n + (L>>3), global sub-chunk (L&7)^((L>>3)&7)  (XOR swizzle)
    int rgrp = lane >> 3;
    int qg   = (lane & 7) ^ (rgrp & 7);
    size_t lgoff = (size_t)rgrp * 1024 + (size_t)qg * 16;   // within chunk-0 row group
    int swz = c & 7;                                        // fragment-read swizzle key

    for (int k0 = 0; k0 < D; k0 += 64) {
        size_t kb = (size_t)k0 * 2;
        #pragma unroll
        for (int m = 0; m < 4; m++) {
            int n = 4 * w + m;
            gll16(Asrc + kb + (size_t)n * 8192 + lgoff, (char*)As + n * 1024);
            gll16(Bsrc + kb + (size_t)n * 8192 + lgoff, (char*)Bs + n * 1024);
        }
        __syncthreads();
        #pragma unroll
        for (int s = 0; s < 2; s++) {
            bf16x8 af[4], bf[4];
            #pragma unroll
            for (int f = 0; f < 4; f++) {
                af[f] = *(const bf16x8*)&As[(wr * 64 + f * 16 + c) * 64 + ((s * 4 + q4) ^ swz) * 8];
                bf[f] = *(const bf16x8*)&Bs[(wc * 64 + f * 16 + c) * 64 + ((s * 4 + q4) ^ swz) * 8];
            }
            #pragma unroll
            for (int fr = 0; fr < 4; fr++)
                #pragma unroll
                for (int fc = 0; fc < 4; fc++)
                    acc[fr][fc] = MFMA16(af[fr], bf[fc], acc[fr][fc]);
        }
        __syncthreads();
    }

    const float* rn  = rnorm + b * LQ;
    const float* seg = segments + (size_t)b * LQ * 2;
    unsigned char* mbase = mask + ((size_t)b << 20);
    #pragma unroll
    for (int fr = 0; fr < 4; fr++) {
        int anyun = 0;
        #pragma unroll
        for (int r = 0; r < 4; r++) {
            int i = i0 + wr * 64 + fr * 16 + q4 * 4 + r;
            float rni = rn[i];
            float ci = seg[i * 2], li = seg[i * 2 + 1];
            float si = ci - li * 0.5f, ei = ci + li * 0.5f;
            #pragma unroll
            for (int fc = 0; fc < 4; fc++) {
                int j = j0 + wc * 64 + fc * 16 + c;
                float rnj = rn[j];
                float cosv = acc[fr][fc][r] * rni * rnj;
                if (fabsf(cosv - COS_THR) < 3e-3f) {   // exact recompute (rare)
                    const float* hri = h + ((size_t)b * LQ + i) * D;
                    const float* hrj = h + ((size_t)b * LQ + j) * D;
                    double dd = 0.0;
                    for (int k = 0; k < D; k++) dd += (double)hri[k] * (double)hrj[k];
                    cosv = (float)(dd * (double)rni * (double)rnj);
                }
                float cj = seg[j * 2], lj = seg[j * 2 + 1];
                float sj = cj - lj * 0.5f, ej = cj + lj * 0.5f;
                float inter = fmaxf(fminf(ei, ej) - fmaxf(si, sj), 0.0f);
                float uni   = li + lj - inter;
                float iou   = inter / uni;
                bool adj = ((iou <= IOU_THR) || (i == j)) && (cosv > COS_THR);
                mbase[(size_t)i * LQ + j] = adj ? 0 : 1;   // 1 = masked
                anyun |= adj ? 1 : 0;
            }
        }
        if (anyun) atomicOr(&summ_lds[wr * 4 + fr][wc], 1);
    }
    __syncthreads();
    if (tid < 16) {
        int lit = tid >> 1, ljt = tid & 1;
        summ[((size_t)b * 64 + (i0 >> 4) + lit) * 16 + (j0 >> 6) + ljt] =
            summ_lds[lit][ljt] ? 1 : 0;
    }
}

// ---------------------------------------------------------------------------
// Kernel 4: QKV bf16 MFMA GEMM, m97-style staged 128x128 tile.
// Outputs: Qb/Kb [b][h][i][dh], Vt [b][h][dh][i]
// ---------------------------------------------------------------------------
__global__ __launch_bounds__(256) void qkv_kernel(const unsigned short* __restrict__ hb,
                                                  const unsigned short* __restrict__ Wb,
                                                  const float* __restrict__ bq,
                                                  const float* __restrict__ bk,
                                                  const float* __restrict__ bv,
                                                  unsigned short* __restrict__ Qb,
                                                  unsigned short* __restrict__ Kb,
                                                  unsigned short* __restrict__ Vt) {
    __shared__ short As[128 * 32], Bs[128 * 32];
    int z = blockIdx.z;
    const unsigned short* W = Wb + (size_t)z * D * D;
    const float* bias = (z == 0) ? bq : (z == 1) ? bk : bv;
    int m0 = blockIdx.x * 128, n0 = blockIdx.y * 128;
    int tid = threadIdx.x, w = tid >> 6, lane = tid & 63;
    int c = lane & 15, q4 = lane >> 4;
    int wr = w >> 1, wc = w & 1;

    f32x4 acc[4][4] = {};
    const char* Asrc = (const char*)(hb + (size_t)m0 * D);
    const char* Bsrc = (const char*)(W + (size_t)n0 * D);
    int ch0 = 2 * w;
    int o0 = ch0 * 1024 + lane * 16;
    int o1 = o0 + 1024;
    size_t g0 = (size_t)(o0 >> 6) * 1024 + (size_t)(o0 & 63);
    size_t g1 = (size_t)(o1 >> 6) * 1024 + (size_t)(o1 & 63);

    for (int k0 = 0; k0 < D; k0 += 32) {
        size_t kb = (size_t)k0 * 2;
        gll16(Asrc + kb + g0, (char*)As + ch0 * 1024);
        gll16(Asrc + kb + g1, (char*)As + ch0 * 1024 + 1024);
        gll16(Bsrc + kb + g0, (char*)Bs + ch0 * 1024);
        gll16(Bsrc + kb + g1, (char*)Bs + ch0 * 1024 + 1024);
        __syncthreads();
        bf16x8 af[4], bf[4];
        #pragma unroll
        for (int f = 0; f < 4; f++) {
            af[f] = *(const bf16x8*)&As[(wr * 64 + f * 16 + c) * 32 + q4 * 8];
            bf[f] = *(const bf16x8*)&Bs[(wc * 64 + f * 16 + c) * 32 + q4 * 8];
        }
        #pragma unroll
        for (int fr = 0; fr < 4; fr++)
            #pragma unroll
            for (int fc = 0; fc < 4; fc++)
                acc[fr][fc] = MFMA16(af[fr], bf[fc], acc[fr][fc]);
        __syncthreads();
    }

    #pragma unroll
    for (int fr = 0; fr < 4; fr++)
        #pragma unroll
        for (int r = 0; r < 4; r++) {
            int m = m0 + wr * 64 + fr * 16 + q4 * 4 + r;
            int b = m >> 10, i = m & 1023;
            #pragma unroll
            for (int fc = 0; fc < 4; fc++) {
                int n = n0 + wc * 64 + fc * 16 + c;
                unsigned short us = f2bf(acc[fr][fc][r] + bias[n]);
                int hh = n >> 6, dh = n & 63;
                size_t bh = (size_t)b * NH + hh;
                if (z == 2)
                    Vt[(bh * DH + dh) * LQ + i] = us;
                else {
                    unsigned short* dst = (z == 0) ? Qb : Kb;
                    dst[(bh * LQ + i) * DH + dh] = us;
                }
            }
        }
}

// ---------------------------------------------------------------------------
// Kernel 5: flash MFMA attention with summary-driven tile skipping.
// ---------------------------------------------------------------------------
__global__ __launch_bounds__(256) void attn_kernel(const unsigned short* __restrict__ Qb,
                                                   const unsigned short* __restrict__ Kb,
                                                   const unsigned short* __restrict__ Vt,
                                                   const unsigned char* __restrict__ mask,
                                                   const unsigned char* __restrict__ summ,
                                                   const float* __restrict__ h,
                                                   float* __restrict__ out) {
    int tid = threadIdx.x;
    int w = tid >> 6, lane = tid & 63;
    int c = lane & 15, q4 = lane >> 4;
    int hh = blockIdx.y, b = blockIdx.z;
    int i0 = blockIdx.x * 64 + w * 16;
    size_t bh = (size_t)b * NH + hh;

    __shared__ unsigned short p_lds[4][16][72];

    const unsigned short* Qrow = Qb + (bh * LQ + i0 + c) * DH;
    bf16x8 qa0 = *(const bf16x8*)(Qrow + q4 * 8);
    bf16x8 qa1 = *(const bf16x8*)(Qrow + 32 + q4 * 8);

    f32x4 O[4] = {};
    float m_r[4] = {NEG, NEG, NEG, NEG};
    float l_r[4] = {0.f, 0.f, 0.f, 0.f};

    const unsigned short* Kbase = Kb + bh * LQ * DH;
    const unsigned short* Vbase = Vt + bh * DH * LQ;
    const unsigned char*  mbase = mask + ((size_t)b * LQ + i0) * LQ;
    const unsigned char*  srow  = summ + ((size_t)b * 64 + (i0 >> 4)) * 16;

    for (int jt = 0; jt < 16; jt++) {
        if (!srow[jt]) continue;           // fully-masked tile: contributes nothing
        int j0 = jt * 64;
        f32x4 S[4] = {};
        #pragma unroll
        for (int cb = 0; cb < 4; cb++) {
            const unsigned short* krow = Kbase + (size_t)(j0 + cb * 16 + c) * DH;
            bf16x8 kf0 = *(const bf16x8*)(krow + q4 * 8);
            bf16x8 kf1 = *(const bf16x8*)(krow + 32 + q4 * 8);
            S[cb] = MFMA16(qa0, kf0, S[cb]);
            S[cb] = MFMA16(qa1, kf1, S[cb]);
        }
        float p[4][4];
        float tmax[4] = {NEG, NEG, NEG, NEG};
        #pragma unroll
        for (int cb = 0; cb < 4; cb++)
            #pragma unroll
            for (int r = 0; r < 4; r++) {
                float sc = S[cb][r] * 0.125f;
                unsigned char mm = mbase[(size_t)(q4 * 4 + r) * LQ + j0 + cb * 16 + c];
                sc = mm ? NEG : sc;
                p[cb][r] = sc;
                tmax[r] = fmaxf(tmax[r], sc);
            }
        #pragma unroll
        for (int r = 0; r < 4; r++) {
            float v = tmax[r];
            v = fmaxf(v, __shfl_xor(v, 1));
            v = fmaxf(v, __shfl_xor(v, 2));
            v = fmaxf(v, __shfl_xor(v, 4));
            v = fmaxf(v, __shfl_xor(v, 8));
            tmax[r] = v;
        }
        float rsum[4];
        #pragma unroll
        for (int r = 0; r < 4; r++) {
            float mn = fmaxf(m_r[r], tmax[r]);
            float alpha = __expf(m_r[r] - mn);
            m_r[r] = mn;
            l_r[r] *= alpha;
            #pragma unroll
            for (int cb2 = 0; cb2 < 4; cb2++) O[cb2][r] *= alpha;
            float s0 = 0.f;
            #pragma unroll
            for (int cb = 0; cb < 4; cb++) {
                float e = __expf(p[cb][r] - mn);
                p[cb][r] = e;
                s0 += e;
            }
            rsum[r] = s0;
        }
        #pragma unroll
        for (int r = 0; r < 4; r++) {
            float v = rsum[r];
            v += __shfl_xor(v, 1);
            v += __shfl_xor(v, 2);
            v += __shfl_xor(v, 4);
            v += __shfl_xor(v, 8);
            l_r[r] += v;
        }
        #pragma unroll
        for (int cb = 0; cb < 4; cb++)
            #pragma unroll
            for (int r = 0; r < 4; r++)
                p_lds[w][q4 * 4 + r][cb * 16 + c] = f2bf(p[cb][r]);
        // per-wave LDS: wave-internal lgkmcnt ordering suffices, no barrier
        #pragma unroll
        for (int s = 0; s < 2; s++) {
            bf16x8 pf = *(const bf16x8*)&p_lds[w][c][s * 32 + q4 * 8];
            #pragma unroll
            for (int cb = 0; cb < 4; cb++) {
                bf16x8 vf = *(const bf16x8*)(Vbase + (size_t)(cb * 16 + c) * LQ + j0 + s * 32 + q4 * 8);
                O[cb] = MFMA16(pf, vf, O[cb]);
            }
        }
    }
    #pragma unroll
    for (int r = 0; r < 4; r++) {
        int i = i0 + q4 * 4 + r;
        float inv = 1.0f / l_r[r];
        #pragma unroll
        for (int cb = 0; cb < 4; cb++) {
            int col = hh * 64 + cb * 16 + c;
            float val = O[cb][r] * inv + h[((size_t)b * LQ + i) * D + col];
            out[((size_t)i * BZ + b) * D + col] = val;
        }
    }
}

// ---------------------------------------------------------------------------
extern "C" void kernel_launch(void* const* d_in, const int* in_sizes, int n_in,
                              void* d_out, int out_size, void* d_ws, size_t ws_size,
                              hipStream_t stream) {
    const float* query    = (const float*)d_in[0];
    const float* segments = (const float*)d_in[1];
    const float* Wq = (const float*)d_in[2];
    const float* bq = (const float*)d_in[3];
    const float* Wk = (const float*)d_in[4];
    const float* bk = (const float*)d_in[5];
    const float* Wv = (const float*)d_in[6];
    const float* bv = (const float*)d_in[7];
    float* out = (float*)d_out;

    const size_t NTOK = (size_t)BZ * LQ;
    char* ws = (char*)d_ws;
    float*          h     = (float*)ws;            ws += NTOK * D * 4;          // 16 MB
    unsigned short* hbuf  = (unsigned short*)ws;   ws += NTOK * D * 2;          // 8 MB (hi)
    unsigned short* Qb    = (unsigned short*)ws;   ws += NTOK * D * 2;          // 8 MB
    unsigned short* Kb    = (unsigned short*)ws;   ws += NTOK * D * 2;          // 8 MB
    unsigned short* Vt    = (unsigned short*)ws;   ws += NTOK * D * 2;          // 8 MB
    unsigned short* Wb    = (unsigned short*)ws;   ws += (size_t)3 * D * D * 2; // 1.5 MB
    float*          rnorm = (float*)ws;            ws += NTOK * 4;              // 32 KB
    unsigned char*  mask  = (unsigned char*)ws;    ws += (size_t)BZ * LQ * LQ;  // 8 MB
    unsigned char*  summ  = (unsigned char*)ws;    /* 8 KB: [b][it(64)][jt(16)] */

    prep_kernel<<<NTOK, 256, 0, stream>>>(query, h, hbuf, rnorm);
    cvt_w_kernel<<<3 * D * D / 4 / 256, 256, 0, stream>>>(Wq, Wk, Wv, Wb);
    mask_kernel<<<dim3(LQ / 128, LQ / 128, BZ), 256, 0, stream>>>(hbuf, h, rnorm,
                                                                  segments, mask, summ);
    qkv_kernel<<<dim3(NTOK / 128, D / 128, 3), 256, 0, stream>>>(hbuf, Wb, bq, bk, bv,
                                                                 Qb, Kb, Vt);
    attn_kernel<<<dim3(LQ / 64, NH, BZ), 256, 0, stream>>>(Qb, Kb, Vt, mask, summ, h, out);
}

// Round 5
// 155.681 us; speedup vs baseline: 26.0252x; 1.2002x over previous
//
#include <hip/hip_runtime.h>
#include <math.h>

#define LQ 1024
#define BZ 8
#define D  512
#define NH 8
#define DH 64
#define IOU_THR 0.2f
#define COS_THR 0.2f
#define NEG (-1e30f)
#define FIXCAP 16384

typedef short bf16x8 __attribute__((ext_vector_type(8)));
typedef float f32x4  __attribute__((ext_vector_type(4)));

#define MFMA16(a, b, cacc) __builtin_amdgcn_mfma_f32_16x16x32_bf16(a, b, cacc, 0, 0, 0)

__device__ inline unsigned short f2bf(float x) {
    union { float f; unsigned int u; } v; v.f = x;
    unsigned int r = v.u + 0x7FFF + ((v.u >> 16) & 1);
    return (unsigned short)(r >> 16);
}

// async global->LDS, 16B per lane. LDS base wave-uniform; HW adds lane*16.
__device__ __forceinline__ void gll16(const void* g, void* ldsbase) {
    __builtin_amdgcn_global_load_lds(
        (const __attribute__((address_space(1))) unsigned int*)g,
        (__attribute__((address_space(3))) unsigned int*)ldsbase, 16, 0, 0);
}

// ---------------------------------------------------------------------------
// Kernel 1: transpose query -> h (fp32) + hi (bf16); rnorm
// ---------------------------------------------------------------------------
__global__ __launch_bounds__(256) void prep_kernel(const float* __restrict__ query,
                                                   float* __restrict__ h,
                                                   unsigned short* __restrict__ hi,
                                                   float* __restrict__ rnorm) {
    int blk = blockIdx.x;            // b*LQ + i
    int b = blk >> 10, i = blk & 1023;
    const float* src = query + ((size_t)i * BZ + b) * D;
    int tid = threadIdx.x;
    float2 v = ((const float2*)src)[tid];
    ((float2*)(h + (size_t)blk * D))[tid] = v;
    unsigned short hx = f2bf(v.x), hy = f2bf(v.y);
    ((unsigned int*)(hi + (size_t)blk * D))[tid] = (unsigned int)hx | ((unsigned int)hy << 16);
    float ss = v.x * v.x + v.y * v.y;
    __shared__ float red[256];
    red[tid] = ss; __syncthreads();
    for (int s = 128; s > 0; s >>= 1) {
        if (tid < s) red[tid] += red[tid + s];
        __syncthreads();
    }
    if (tid == 0) rnorm[blk] = 1.0f / fmaxf(sqrtf(red[0]), 1e-8f);
}

// ---------------------------------------------------------------------------
// Kernel 2: Wq/Wk/Wv fp32 -> bf16
// ---------------------------------------------------------------------------
__global__ __launch_bounds__(256) void cvt_w_kernel(const float* __restrict__ Wq,
                                                    const float* __restrict__ Wk,
                                                    const float* __restrict__ Wv,
                                                    unsigned short* __restrict__ Wb) {
    int t = blockIdx.x * 256 + threadIdx.x;
    int mat = t >> 16;
    int off = (t & 65535) * 4;
    const float* src = (mat == 0) ? Wq : (mat == 1) ? Wk : Wv;
    float4 v = *(const float4*)(src + off);
    uint2 p;
    p.x = (unsigned int)f2bf(v.x) | ((unsigned int)f2bf(v.y) << 16);
    p.y = (unsigned int)f2bf(v.z) | ((unsigned int)f2bf(v.w) << 16);
    *(uint2*)(Wb + (size_t)mat * D * D + off) = p;
}

// ---------------------------------------------------------------------------
// Kernel 3: mask via hi-only bf16 MFMA. Near-threshold elements are APPENDED
// to a fixup list (no inline fp64 — that was a ~50us straggler tail).
// 128x128 tile, BK=64, XOR-swizzled gll16 staging (conflict-free ds_read).
// ---------------------------------------------------------------------------
__global__ __launch_bounds__(256) void mask_kernel(const unsigned short* __restrict__ hi,
                                                   const float* __restrict__ rnorm,
                                                   const float* __restrict__ segments,
                                                   unsigned char* __restrict__ mask,
                                                   unsigned char* __restrict__ summ,
                                                   int* __restrict__ fix_cnt,
                                                   unsigned int* __restrict__ fix_list) {
    __shared__ short As[128 * 64], Bs[128 * 64];   // 16 KB each
    __shared__ float4 iSE[128], jSE[128];          // (s, e, l, rnorm)
    __shared__ int summ_lds[8][2];
    int b = blockIdx.z, i0 = blockIdx.y * 128, j0 = blockIdx.x * 128;
    int tid = threadIdx.x, w = tid >> 6, lane = tid & 63;
    int c = lane & 15, q4 = lane >> 4;
    int wr = w >> 1, wc = w & 1;
    if (tid < 16) summ_lds[tid >> 1][tid & 1] = 0;

    f32x4 acc[4][4] = {};
    const char* Asrc = (const char*)(hi + ((size_t)b * LQ + i0) * D);
    const char* Bsrc = (const char*)(hi + ((size_t)b * LQ + j0) * D);

    // staging: chunk n (1 KB) = rows 8n..8n+7; lane L -> row 8n+(L>>3),
    // global 16B sub-chunk (L&7)^((L>>3)&7) (XOR swizzle)
    int rgrp = lane >> 3;
    int qg   = (lane & 7) ^ (rgrp & 7);
    size_t lgoff = (size_t)rgrp * 1024 + (size_t)qg * 16;
    int swz = c & 7;

    for (int k0 = 0; k0 < D; k0 += 64) {
        size_t kb = (size_t)k0 * 2;
        #pragma unroll
        for (int m = 0; m < 4; m++) {
            int n = 4 * w + m;
            gll16(Asrc + kb + (size_t)n * 8192 + lgoff, (char*)As + n * 1024);
            gll16(Bsrc + kb + (size_t)n * 8192 + lgoff, (char*)Bs + n * 1024);
        }
        __syncthreads();
        #pragma unroll
        for (int s = 0; s < 2; s++) {
            bf16x8 af[4], bf[4];
            #pragma unroll
            for (int f = 0; f < 4; f++) {
                af[f] = *(const bf16x8*)&As[(wr * 64 + f * 16 + c) * 64 + ((s * 4 + q4) ^ swz) * 8];
                bf[f] = *(const bf16x8*)&Bs[(wc * 64 + f * 16 + c) * 64 + ((s * 4 + q4) ^ swz) * 8];
            }
            #pragma unroll
            for (int fr = 0; fr < 4; fr++)
                #pragma unroll
                for (int fc = 0; fc < 4; fc++)
                    acc[fr][fc] = MFMA16(af[fr], bf[fc], acc[fr][fc]);
        }
        __syncthreads();
    }

    // stage segment geometry + rnorm into LDS (coalesced, once per block)
    {
        const float2* seg2 = (const float2*)(segments + (size_t)b * LQ * 2);
        const float* rn = rnorm + b * LQ;
        if (tid < 128) {
            int i = i0 + tid;
            float2 cl = seg2[i];
            iSE[tid] = make_float4(cl.x - cl.y * 0.5f, cl.x + cl.y * 0.5f, cl.y, rn[i]);
        } else {
            int j = j0 + tid - 128;
            float2 cl = seg2[j];
            jSE[tid - 128] = make_float4(cl.x - cl.y * 0.5f, cl.x + cl.y * 0.5f, cl.y, rn[j]);
        }
        __syncthreads();
    }

    unsigned char* mbase = mask + ((size_t)b << 20);
    #pragma unroll
    for (int fr = 0; fr < 4; fr++) {
        int anyun = 0;
        #pragma unroll
        for (int r = 0; r < 4; r++) {
            int il = wr * 64 + fr * 16 + q4 * 4 + r;
            int i = i0 + il;
            float4 I = iSE[il];
            #pragma unroll
            for (int fc = 0; fc < 4; fc++) {
                int jl = wc * 64 + fc * 16 + c;
                int j = j0 + jl;
                float4 J = jSE[jl];
                float cosv = acc[fr][fc][r] * I.w * J.w;
                if (fabsf(cosv - COS_THR) < 1.5e-3f) {     // defer exact recompute
                    int idx = atomicAdd(fix_cnt, 1);
                    if (idx < FIXCAP)
                        fix_list[idx] = ((unsigned int)b << 20) | ((unsigned int)i << 10) | j;
                }
                float inter = fmaxf(fminf(I.y, J.y) - fmaxf(I.x, J.x), 0.0f);
                float uni   = I.z + J.z - inter;
                float iou   = inter / uni;
                bool adj = ((iou <= IOU_THR) || (i == j)) && (cosv > COS_THR);
                mbase[(size_t)i * LQ + j] = adj ? 0 : 1;   // 1 = masked
                anyun |= adj ? 1 : 0;
            }
        }
        if (anyun) atomicOr(&summ_lds[wr * 4 + fr][wc], 1);
    }
    __syncthreads();
    if (tid < 16) {
        int lit = tid >> 1, ljt = tid & 1;
        summ[((size_t)b * 64 + (i0 >> 4) + lit) * 16 + (j0 >> 6) + ljt] =
            summ_lds[lit][ljt] ? 1 : 0;
    }
}

// ---------------------------------------------------------------------------
// Kernel 3b: fixup — one wave per flagged element; cooperative fp64 dot.
// Patches mask byte; may set summ=1 (stale summ=1 is safe: online softmax
// self-heals fully-masked tiles once the diagonal tile is processed).
// ---------------------------------------------------------------------------
__global__ __launch_bounds__(64) void fixup_kernel(const float* __restrict__ h,
                                                   const float* __restrict__ rnorm,
                                                   const float* __restrict__ segments,
                                                   const int* __restrict__ fix_cnt,
                                                   const unsigned int* __restrict__ fix_list,
                                                   unsigned char* __restrict__ mask,
                                                   unsigned char* __restrict__ summ) {
    int cnt = *fix_cnt; if (cnt > FIXCAP) cnt = FIXCAP;
    int lane = threadIdx.x;
    for (int e = blockIdx.x; e < cnt; e += gridDim.x) {
        unsigned int pk = fix_list[e];
        int b = pk >> 20, i = (pk >> 10) & 1023, j = pk & 1023;
        const float* hri = h + ((size_t)b * LQ + i) * D;
        const float* hrj = h + ((size_t)b * LQ + j) * D;
        double dd = 0.0;
        #pragma unroll
        for (int k = 0; k < D / 64; k++)
            dd += (double)hri[k * 64 + lane] * (double)hrj[k * 64 + lane];
        #pragma unroll
        for (int s = 1; s < 64; s <<= 1) dd += __shfl_xor(dd, s);
        if (lane == 0) {
            float rni = rnorm[b * LQ + i], rnj = rnorm[b * LQ + j];
            float cosv = (float)(dd * (double)rni * (double)rnj);
            const float* seg = segments + (size_t)b * LQ * 2;
            float ci = seg[i * 2], li = seg[i * 2 + 1];
            float cj = seg[j * 2], lj = seg[j * 2 + 1];
            float si = ci - li * 0.5f, ei = ci + li * 0.5f;
            float sj = cj - lj * 0.5f, ej = cj + lj * 0.5f;
            float inter = fmaxf(fminf(ei, ej) - fmaxf(si, sj), 0.0f);
            float iou = inter / (li + lj - inter);
            bool adj = ((iou <= IOU_THR) || (i == j)) && (cosv > COS_THR);
            mask[((size_t)b * LQ + i) * LQ + j] = adj ? 0 : 1;
            if (adj) summ[((size_t)b * 64 + (i >> 4)) * 16 + (j >> 6)] = 1;
        }
    }
}

// ---------------------------------------------------------------------------
// Kernel 4: QKV bf16 MFMA GEMM, 128x128 tile, BK=64 XOR-swizzled staging.
// Outputs: Qb/Kb [b][h][i][dh], Vt [b][h][dh][i]
// ---------------------------------------------------------------------------
__global__ __launch_bounds__(256) void qkv_kernel(const unsigned short* __restrict__ hb,
                                                  const unsigned short* __restrict__ Wb,
                                                  const float* __restrict__ bq,
                                                  const float* __restrict__ bk,
                                                  const float* __restrict__ bv,
                                                  unsigned short* __restrict__ Qb,
                                                  unsigned short* __restrict__ Kb,
                                                  unsigned short* __restrict__ Vt) {
    __shared__ short As[128 * 64], Bs[128 * 64];
    int z = blockIdx.z;
    const unsigned short* W = Wb + (size_t)z * D * D;
    const float* bias = (z == 0) ? bq : (z == 1) ? bk : bv;
    int m0 = blockIdx.x * 128, n0 = blockIdx.y * 128;
    int tid = threadIdx.x, w = tid >> 6, lane = tid & 63;
    int c = lane & 15, q4 = lane >> 4;
    int wr = w >> 1, wc = w & 1;

    f32x4 acc[4][4] = {};
    const char* Asrc = (const char*)(hb + (size_t)m0 * D);
    const char* Bsrc = (const char*)(W + (size_t)n0 * D);
    int rgrp = lane >> 3;
    int qg   = (lane & 7) ^ (rgrp & 7);
    size_t lgoff = (size_t)rgrp * 1024 + (size_t)qg * 16;
    int swz = c & 7;

    for (int k0 = 0; k0 < D; k0 += 64) {
        size_t kb = (size_t)k0 * 2;
        #pragma unroll
        for (int m = 0; m < 4; m++) {
            int n = 4 * w + m;
            gll16(Asrc + kb + (size_t)n * 8192 + lgoff, (char*)As + n * 1024);
            gll16(Bsrc + kb + (size_t)n * 8192 + lgoff, (char*)Bs + n * 1024);
        }
        __syncthreads();
        #pragma unroll
        for (int s = 0; s < 2; s++) {
            bf16x8 af[4], bf[4];
            #pragma unroll
            for (int f = 0; f < 4; f++) {
                af[f] = *(const bf16x8*)&As[(wr * 64 + f * 16 + c) * 64 + ((s * 4 + q4) ^ swz) * 8];
                bf[f] = *(const bf16x8*)&Bs[(wc * 64 + f * 16 + c) * 64 + ((s * 4 + q4) ^ swz) * 8];
            }
            #pragma unroll
            for (int fr = 0; fr < 4; fr++)
                #pragma unroll
                for (int fc = 0; fc < 4; fc++)
                    acc[fr][fc] = MFMA16(af[fr], bf[fc], acc[fr][fc]);
        }
        __syncthreads();
    }

    #pragma unroll
    for (int fr = 0; fr < 4; fr++)
        #pragma unroll
        for (int r = 0; r < 4; r++) {
            int m = m0 + wr * 64 + fr * 16 + q4 * 4 + r;
            int b = m >> 10, i = m & 1023;
            #pragma unroll
            for (int fc = 0; fc < 4; fc++) {
                int n = n0 + wc * 64 + fc * 16 + c;
                unsigned short us = f2bf(acc[fr][fc][r] + bias[n]);
                int hh = n >> 6, dh = n & 63;
                size_t bh = (size_t)b * NH + hh;
                if (z == 2)
                    Vt[(bh * DH + dh) * LQ + i] = us;
                else {
                    unsigned short* dst = (z == 0) ? Qb : Kb;
                    dst[(bh * LQ + i) * DH + dh] = us;
                }
            }
        }
}

// ---------------------------------------------------------------------------
// Kernel 5: flash MFMA attention with summary-driven tile skipping.
// ---------------------------------------------------------------------------
__global__ __launch_bounds__(256) void attn_kernel(const unsigned short* __restrict__ Qb,
                                                   const unsigned short* __restrict__ Kb,
                                                   const unsigned short* __restrict__ Vt,
                                                   const unsigned char* __restrict__ mask,
                                                   const unsigned char* __restrict__ summ,
                                                   const float* __restrict__ h,
                                                   float* __restrict__ out) {
    int tid = threadIdx.x;
    int w = tid >> 6, lane = tid & 63;
    int c = lane & 15, q4 = lane >> 4;
    int hh = blockIdx.y, b = blockIdx.z;
    int i0 = blockIdx.x * 64 + w * 16;
    size_t bh = (size_t)b * NH + hh;

    __shared__ unsigned short p_lds[4][16][72];

    const unsigned short* Qrow = Qb + (bh * LQ + i0 + c) * DH;
    bf16x8 qa0 = *(const bf16x8*)(Qrow + q4 * 8);
    bf16x8 qa1 = *(const bf16x8*)(Qrow + 32 + q4 * 8);

    f32x4 O[4] = {};
    float m_r[4] = {NEG, NEG, NEG, NEG};
    float l_r[4] = {0.f, 0.f, 0.f, 0.f};

    const unsigned short* Kbase = Kb + bh * LQ * DH;
    const unsigned short* Vbase = Vt + bh * DH * LQ;
    const unsigned char*  mbase = mask + ((size_t)b * LQ + i0) * LQ;
    const unsigned char*  srow  = summ + ((size_t)b * 64 + (i0 >> 4)) * 16;

    for (int jt = 0; jt < 16; jt++) {
        if (!srow[jt]) continue;           // fully-masked tile: contributes nothing
        int j0 = jt * 64;
        f32x4 S[4] = {};
        #pragma unroll
        for (int cb = 0; cb < 4; cb++) {
            const unsigned short* krow = Kbase + (size_t)(j0 + cb * 16 + c) * DH;
            bf16x8 kf0 = *(const bf16x8*)(krow + q4 * 8);
            bf16x8 kf1 = *(const bf16x8*)(krow + 32 + q4 * 8);
            S[cb] = MFMA16(qa0, kf0, S[cb]);
            S[cb] = MFMA16(qa1, kf1, S[cb]);
        }
        float p[4][4];
        float tmax[4] = {NEG, NEG, NEG, NEG};
        #pragma unroll
        for (int cb = 0; cb < 4; cb++)
            #pragma unroll
            for (int r = 0; r < 4; r++) {
                float sc = S[cb][r] * 0.125f;
                unsigned char mm = mbase[(size_t)(q4 * 4 + r) * LQ + j0 + cb * 16 + c];
                sc = mm ? NEG : sc;
                p[cb][r] = sc;
                tmax[r] = fmaxf(tmax[r], sc);
            }
        #pragma unroll
        for (int r = 0; r < 4; r++) {
            float v = tmax[r];
            v = fmaxf(v, __shfl_xor(v, 1));
            v = fmaxf(v, __shfl_xor(v, 2));
            v = fmaxf(v, __shfl_xor(v, 4));
            v = fmaxf(v, __shfl_xor(v, 8));
            tmax[r] = v;
        }
        float rsum[4];
        #pragma unroll
        for (int r = 0; r < 4; r++) {
            float mn = fmaxf(m_r[r], tmax[r]);
            float alpha = __expf(m_r[r] - mn);
            m_r[r] = mn;
            l_r[r] *= alpha;
            #pragma unroll
            for (int cb2 = 0; cb2 < 4; cb2++) O[cb2][r] *= alpha;
            float s0 = 0.f;
            #pragma unroll
            for (int cb = 0; cb < 4; cb++) {
                float e = __expf(p[cb][r] - mn);
                p[cb][r] = e;
                s0 += e;
            }
            rsum[r] = s0;
        }
        #pragma unroll
        for (int r = 0; r < 4; r++) {
            float v = rsum[r];
            v += __shfl_xor(v, 1);
            v += __shfl_xor(v, 2);
            v += __shfl_xor(v, 4);
            v += __shfl_xor(v, 8);
            l_r[r] += v;
        }
        #pragma unroll
        for (int cb = 0; cb < 4; cb++)
            #pragma unroll
            for (int r = 0; r < 4; r++)
                p_lds[w][q4 * 4 + r][cb * 16 + c] = f2bf(p[cb][r]);
        // per-wave LDS: wave-internal lgkmcnt ordering suffices, no barrier
        #pragma unroll
        for (int s = 0; s < 2; s++) {
            bf16x8 pf = *(const bf16x8*)&p_lds[w][c][s * 32 + q4 * 8];
            #pragma unroll
            for (int cb = 0; cb < 4; cb++) {
                bf16x8 vf = *(const bf16x8*)(Vbase + (size_t)(cb * 16 + c) * LQ + j0 + s * 32 + q4 * 8);
                O[cb] = MFMA16(pf, vf, O[cb]);
            }
        }
    }
    #pragma unroll
    for (int r = 0; r < 4; r++) {
        int i = i0 + q4 * 4 + r;
        float inv = 1.0f / l_r[r];
        #pragma unroll
        for (int cb = 0; cb < 4; cb++) {
            int col = hh * 64 + cb * 16 + c;
            float val = O[cb][r] * inv + h[((size_t)b * LQ + i) * D + col];
            out[((size_t)i * BZ + b) * D + col] = val;
        }
    }
}

// ---------------------------------------------------------------------------
extern "C" void kernel_launch(void* const* d_in, const int* in_sizes, int n_in,
                              void* d_out, int out_size, void* d_ws, size_t ws_size,
                              hipStream_t stream) {
    const float* query    = (const float*)d_in[0];
    const float* segments = (const float*)d_in[1];
    const float* Wq = (const float*)d_in[2];
    const float* bq = (const float*)d_in[3];
    const float* Wk = (const float*)d_in[4];
    const float* bk = (const float*)d_in[5];
    const float* Wv = (const float*)d_in[6];
    const float* bv = (const float*)d_in[7];
    float* out = (float*)d_out;

    const size_t NTOK = (size_t)BZ * LQ;
    char* ws = (char*)d_ws;
    float*          h     = (float*)ws;            ws += NTOK * D * 4;          // 16 MB
    unsigned short* hbuf  = (unsigned short*)ws;   ws += NTOK * D * 2;          // 8 MB
    unsigned short* Qb    = (unsigned short*)ws;   ws += NTOK * D * 2;          // 8 MB
    unsigned short* Kb    = (unsigned short*)ws;   ws += NTOK * D * 2;          // 8 MB
    unsigned short* Vt    = (unsigned short*)ws;   ws += NTOK * D * 2;          // 8 MB
    unsigned short* Wb    = (unsigned short*)ws;   ws += (size_t)3 * D * D * 2; // 1.5 MB
    float*          rnorm = (float*)ws;            ws += NTOK * 4;              // 32 KB
    unsigned char*  mask  = (unsigned char*)ws;    ws += (size_t)BZ * LQ * LQ;  // 8 MB
    unsigned char*  summ  = (unsigned char*)ws;    ws += 8192;                  // 8 KB
    int*            fix_cnt = (int*)ws;            ws += 64;
    unsigned int*   fix_list = (unsigned int*)ws;  /* 64 KB */

    hipMemsetAsync(fix_cnt, 0, 64, stream);
    prep_kernel<<<NTOK, 256, 0, stream>>>(query, h, hbuf, rnorm);
    cvt_w_kernel<<<3 * D * D / 4 / 256, 256, 0, stream>>>(Wq, Wk, Wv, Wb);
    mask_kernel<<<dim3(LQ / 128, LQ / 128, BZ), 256, 0, stream>>>(hbuf, rnorm, segments,
                                                                  mask, summ, fix_cnt, fix_list);
    fixup_kernel<<<64, 64, 0, stream>>>(h, rnorm, segments, fix_cnt, fix_list, mask, summ);
    qkv_kernel<<<dim3(NTOK / 128, D / 128, 3), 256, 0, stream>>>(hbuf, Wb, bq, bk, bv,
                                                                 Qb, Kb, Vt);
    attn_kernel<<<dim3(LQ / 64, NH, BZ), 256, 0, stream>>>(Qb, Kb, Vt, mask, summ, h, out);
}